// Round 1
// baseline (530.417 us; speedup 1.0000x reference)
//
#include <hip/hip_runtime.h>
#include <math.h>

#define B 8
#define FCH 32
#define WI 256
#define HI 256
#define NW 32
#define NH 32
#define NBOX 1024
#define K 25
#define S 28
#define DZI 16
#define FEAT_FLAT (FCH*S*S)   /* 25088 */
#define OUT_FLAT (2*S*S)      /* 1568 */
#define SMIN 24.0f
#define SMAX 96.0f
#define BIG_SZ (K*B*WI*HI)    /* 13,107,200 */

/* output offsets (floats), in reference return order */
#define O_LOGIT_MU    0
#define O_LOGIT_FEW   8192
#define O_BIG_MASK    8392
#define O_BIG_MASK_NON (O_BIG_MASK + BIG_SZ)
#define O_BIG_IMG     (O_BIG_MASK_NON + BIG_SZ)
#define O_P_MAP       (O_BIG_IMG + BIG_SZ)
#define O_C_FEW       (O_P_MAP + 8192)
#define O_BX          (O_C_FEW + 200)
#define O_BY          (O_BX + 200)
#define O_BW          (O_BY + 200)
#define O_BH          (O_BW + 200)
#define O_Z_SAMPLE    (O_BH + 200)
#define O_KL_LOGIT    (O_Z_SAMPLE + 3200)
#define O_KL_ZWHERE   (O_KL_LOGIT + 8192)
#define O_KL_ZINST    (O_KL_ZWHERE + 800)

__device__ __forceinline__ float sigmoidf_(float x) { return 1.0f / (1.0f + expf(-x)); }
__device__ __forceinline__ float softplusf_(float x) { return fmaxf(x, 0.0f) + log1pf(expf(-fabsf(x))); }

__device__ __forceinline__ float tap256(const float* img, int x, int y) {
    bool in = ((unsigned)x < 256u) && ((unsigned)y < 256u);
    int xc = min(max(x, 0), 255), yc = min(max(y, 0), 255);
    float v = img[xc * 256 + yc];
    return in ? v : 0.0f;
}

__device__ __forceinline__ float tap28(const float* img, int x, int y) {
    bool in = ((unsigned)x < 28u) && ((unsigned)y < 28u);
    int xc = min(max(x, 0), 27), yc = min(max(y, 0), 27);
    float v = img[xc * 28 + yc];
    return in ? v : 0.0f;
}

/* ---------------- kernel M: elementwise logit maps ---------------- */
__global__ void misc_kernel(const float* __restrict__ logit_mu, float* __restrict__ out) {
    int i = blockIdx.x * blockDim.x + threadIdx.x;
    if (i >= B * NBOX) return;
    float x = logit_mu[i];
    out[O_LOGIT_MU + i] = x;
    float p = sigmoidf_(x);
    out[O_P_MAP + i] = p;
    out[O_KL_LOGIT + i] = 0.69314718055994531f + p * logf(p + 1e-8f) + (1.0f - p) * logf(1.0f - p + 1e-8f);
}

/* ---------------- kernel T: per-batch top-k + box params + kl_zwhere ---------------- */
__global__ void topk_kernel(const float* __restrict__ logit_mu,
                            const float* __restrict__ zmu, const float* __restrict__ zstd,
                            const float* __restrict__ w_zw, const float* __restrict__ b_zw,
                            float* __restrict__ out, float* __restrict__ ws_boxes) {
    int b = blockIdx.x;
    int lane = threadIdx.x;          // 64 lanes, one wave
    const float* lg = logit_mu + b * NBOX;
    float vals[16];
    #pragma unroll
    for (int m = 0; m < 16; ++m) vals[m] = lg[m * 64 + lane];
    unsigned taken = 0;
    int sel_idx = 0;

    for (int ks = 0; ks < K; ++ks) {
        float bv = -INFINITY; int bi = 0x7fffffff;
        #pragma unroll
        for (int m = 0; m < 16; ++m) {
            if (!(taken & (1u << m))) {
                float v = vals[m]; int idx = m * 64 + lane;
                if (v > bv || (v == bv && idx < bi)) { bv = v; bi = idx; }
            }
        }
        #pragma unroll
        for (int sh = 32; sh >= 1; sh >>= 1) {
            float ov = __shfl_xor(bv, sh);
            int   oi = __shfl_xor(bi, sh);
            if (ov > bv || (ov == bv && oi < bi)) { bv = ov; bi = oi; }
        }
        if ((bi & 63) == lane) taken |= (1u << (bi >> 6));  // owner marks it used
        if (lane == ks) sel_idx = bi;
        if (lane == 0) {
            out[O_LOGIT_FEW + ks * B + b] = bv;
            out[O_C_FEW + ks * B + b] = sigmoidf_(bv);
        }
    }

    if (lane < K) {
        int idx = sel_idx;
        int w = idx >> 5, h = idx & 31;
        float mu_c[4];
        #pragma unroll
        for (int c = 0; c < 4; ++c) mu_c[c] = zmu[((b * 4 + c) * NW + w) * NH + h];
        float t[4];
        #pragma unroll
        for (int o = 0; o < 4; ++o) {
            float a = b_zw[o];
            #pragma unroll
            for (int c = 0; c < 4; ++c) a = fmaf(mu_c[c], w_zw[o * 4 + c], a);
            t[o] = sigmoidf_(a);
        }
        float bx = (float)WI * ((float)w + t[0]) / (float)NW;
        float by = (float)HI * ((float)h + t[1]) / (float)NH;
        float bw = SMIN + (SMAX - SMIN) * t[2];
        float bh = SMIN + (SMAX - SMIN) * t[3];
        int kb = lane * B + b;
        out[O_BX + kb] = bx;
        out[O_BY + kb] = by;
        out[O_BW + kb] = bw;
        out[O_BH + kb] = bh;
        ((float4*)ws_boxes)[kb] = make_float4(bx, by, bw, bh);
        #pragma unroll
        for (int c = 0; c < 4; ++c) {
            float m = mu_c[c];
            float sd = zstd[((b * 4 + c) * NW + w) * NH + h];
            out[O_KL_ZWHERE + kb * 4 + c] = 0.5f * (sd * sd + m * m - 1.0f) - logf(sd);
        }
    }
}

/* ---------------- kernel C: crop (bilinear) + encoder GEMV + kl_zinstance ---------------- */
__global__ __launch_bounds__(256) void crop_enc_kernel(
        const float* __restrict__ features,
        const float* __restrict__ w_mu, const float* __restrict__ b_mu,
        const float* __restrict__ w_std, const float* __restrict__ b_std,
        const float* __restrict__ ws_boxes, float* __restrict__ ws_z, float* __restrict__ out) {
    int kb = blockIdx.x;            // k*8 + b
    int b = kb & 7;
    float4 box = ((const float4*)ws_boxes)[kb];
    float cx = box.x, cy = box.y, cw = box.z, chh = box.w;
    const float* fb = features + (size_t)b * FCH * WI * HI;

    float accm[DZI], accs[DZI];
    #pragma unroll
    for (int j = 0; j < DZI; ++j) { accm[j] = 0.0f; accs[j] = 0.0f; }

    for (int i = threadIdx.x; i < FEAT_FLAT; i += 256) {
        unsigned ui = (unsigned)i;
        unsigned c = ui / 784u;
        unsigned s = ui - c * 784u;
        unsigned ix = s / 28u;
        unsigned iy = s - ix * 28u;
        float px = cx - 0.5f * cw + ((float)ix / 27.0f) * cw;
        float py = cy - 0.5f * chh + ((float)iy / 27.0f) * chh;
        const float* img = fb + (size_t)c * (WI * HI);
        float x0f = floorf(px), y0f = floorf(py);
        float fx = px - x0f, fy = py - y0f;
        int x0 = (int)x0f, y0 = (int)y0f;
        float a00 = tap256(img, x0, y0),     a01 = tap256(img, x0, y0 + 1);
        float a10 = tap256(img, x0 + 1, y0), a11 = tap256(img, x0 + 1, y0 + 1);
        float v = (1.0f - fx) * ((1.0f - fy) * a00 + fy * a01)
                +         fx  * ((1.0f - fy) * a10 + fy * a11);
        #pragma unroll
        for (int j = 0; j < DZI; ++j) {
            accm[j] = fmaf(v, w_mu[j * FEAT_FLAT + i], accm[j]);
            accs[j] = fmaf(v, w_std[j * FEAT_FLAT + i], accs[j]);
        }
    }

    #pragma unroll
    for (int j = 0; j < DZI; ++j) {
        #pragma unroll
        for (int sh = 32; sh >= 1; sh >>= 1) {
            accm[j] += __shfl_xor(accm[j], sh);
            accs[j] += __shfl_xor(accs[j], sh);
        }
    }
    __shared__ float red[4][32];
    int wave = threadIdx.x >> 6;
    int lane = threadIdx.x & 63;
    if (lane == 0) {
        #pragma unroll
        for (int j = 0; j < DZI; ++j) { red[wave][j] = accm[j]; red[wave][16 + j] = accs[j]; }
    }
    __syncthreads();
    if (threadIdx.x < DZI) {
        int j = threadIdx.x;
        float m  = red[0][j] + red[1][j] + red[2][j] + red[3][j] + b_mu[j];
        float sp = red[0][16 + j] + red[1][16 + j] + red[2][16 + j] + red[3][16 + j] + b_std[j];
        float sd = softplusf_(sp);
        out[O_Z_SAMPLE + kb * DZI + j] = m;
        ws_z[kb * DZI + j] = m;
        out[O_KL_ZINST + kb * DZI + j] = 0.5f * (sd * sd + m * m - 1.0f) - logf(sd + 1e-8f);
    }
}

/* ---------------- kernel D: decoder GEMV + activations -> ws_small ---------------- */
__global__ void dec_kernel(const float* __restrict__ ws_z, const float* __restrict__ w_dec,
                           const float* __restrict__ b_dec, float* __restrict__ ws_small) {
    int kb = blockIdx.x;
    __shared__ float z[DZI];
    if (threadIdx.x < DZI) z[threadIdx.x] = ws_z[kb * DZI + threadIdx.x];
    __syncthreads();
    for (int o = threadIdx.x; o < OUT_FLAT; o += 256) {
        float a = b_dec[o];
        #pragma unroll
        for (int j = 0; j < DZI; ++j) a = fmaf(z[j], w_dec[o * DZI + j], a);
        float r = (o < 784) ? softplusf_(a) : sigmoidf_(a);
        ws_small[(size_t)kb * OUT_FLAT + o] = r;
    }
}

/* ---------------- kernel E: uncrop (bilinear) + mask compose ---------------- */
__global__ __launch_bounds__(256) void uncrop_kernel(const float* __restrict__ ws_small,
                                                     const float* __restrict__ ws_boxes,
                                                     float* __restrict__ out) {
    int bu = blockIdx.x;            // b*256 + u
    int b = bu >> 8;
    int u = bu & 255;
    int v = threadIdx.x;

    __shared__ float4 boxes[K];
    if (threadIdx.x < K) boxes[threadIdx.x] = ((const float4*)ws_boxes)[threadIdx.x * B + b];
    __syncthreads();

    float wk[K];
    float sumw = 0.0f;
    #pragma unroll
    for (int k = 0; k < K; ++k) {
        float4 bx = boxes[k];
        float sx = ((float)u - (bx.x - 0.5f * bx.z)) / bx.z * 27.0f;
        float sy = ((float)v - (bx.y - 0.5f * bx.w)) / bx.w * 27.0f;
        float wv = 0.0f, iv = 0.0f;
        if (sx > -1.0f && sx < 28.0f && sy > -1.0f && sy < 28.0f) {
            float x0f = floorf(sx), y0f = floorf(sy);
            float fx = sx - x0f, fy = sy - y0f;
            int x0 = (int)x0f, y0 = (int)y0f;
            const float* p0 = ws_small + (size_t)(k * B + b) * OUT_FLAT;
            const float* p1 = p0 + 784;
            float a00 = tap28(p0, x0, y0),     a01 = tap28(p0, x0, y0 + 1);
            float a10 = tap28(p0, x0 + 1, y0), a11 = tap28(p0, x0 + 1, y0 + 1);
            wv = (1.0f - fx) * ((1.0f - fy) * a00 + fy * a01)
               +         fx  * ((1.0f - fy) * a10 + fy * a11);
            float c00 = tap28(p1, x0, y0),     c01 = tap28(p1, x0, y0 + 1);
            float c10 = tap28(p1, x0 + 1, y0), c11 = tap28(p1, x0 + 1, y0 + 1);
            iv = (1.0f - fx) * ((1.0f - fy) * c00 + fy * c01)
               +         fx  * ((1.0f - fy) * c10 + fy * c11);
        }
        wk[k] = wv;
        sumw += wv;
        size_t base = ((size_t)(k * B + b) * 256 + u) * 256 + v;
        out[O_BIG_IMG + base] = iv;
        out[O_BIG_MASK_NON + base] = tanhf(wv);
    }
    float scale = tanhf(sumw) / fmaxf(sumw, 1e-6f);
    #pragma unroll
    for (int k = 0; k < K; ++k) {
        size_t base = ((size_t)(k * B + b) * 256 + u) * 256 + v;
        out[O_BIG_MASK + base] = wk[k] * scale;
    }
}

extern "C" void kernel_launch(void* const* d_in, const int* in_sizes, int n_in,
                              void* d_out, int out_size, void* d_ws, size_t ws_size,
                              hipStream_t stream) {
    const float* features = (const float*)d_in[1];
    const float* zwhere_mu = (const float*)d_in[2];
    const float* zwhere_std = (const float*)d_in[3];
    const float* logit_mu = (const float*)d_in[4];
    const float* w_zwhere = (const float*)d_in[5];
    const float* b_zwhere = (const float*)d_in[6];
    const float* w_enc_mu = (const float*)d_in[7];
    const float* b_enc_mu = (const float*)d_in[8];
    const float* w_enc_std = (const float*)d_in[9];
    const float* b_enc_std = (const float*)d_in[10];
    const float* w_dec = (const float*)d_in[11];
    const float* b_dec = (const float*)d_in[12];
    float* out = (float*)d_out;

    float* ws_boxes = (float*)d_ws;                   // 200 * float4 = 3200 B
    float* ws_z     = ws_boxes + 200 * 4;             // 200*16 floats = 12800 B
    float* ws_small = ws_z + 200 * DZI;               // 200*1568 floats = 1.25 MB

    hipLaunchKernelGGL(misc_kernel, dim3(32), dim3(256), 0, stream, logit_mu, out);
    hipLaunchKernelGGL(topk_kernel, dim3(B), dim3(64), 0, stream,
                       logit_mu, zwhere_mu, zwhere_std, w_zwhere, b_zwhere, out, ws_boxes);
    hipLaunchKernelGGL(crop_enc_kernel, dim3(K * B), dim3(256), 0, stream,
                       features, w_enc_mu, b_enc_mu, w_enc_std, b_enc_std, ws_boxes, ws_z, out);
    hipLaunchKernelGGL(dec_kernel, dim3(K * B), dim3(256), 0, stream, ws_z, w_dec, b_dec, ws_small);
    hipLaunchKernelGGL(uncrop_kernel, dim3(B * 256), dim3(256), 0, stream, ws_small, ws_boxes, out);
}

// Round 2
// 142.661 us; speedup vs baseline: 3.7180x; 3.7180x over previous
//
#include <hip/hip_runtime.h>
#include <math.h>

#define B 8
#define FCH 32
#define WI 256
#define HI 256
#define NW 32
#define NH 32
#define NBOX 1024
#define K 25
#define S 28
#define DZI 16
#define FEAT_FLAT (FCH*S*S)   /* 25088 */
#define OUT_FLAT (2*S*S)      /* 1568 */
#define SMIN 24.0f
#define SMAX 96.0f
#define BIG_SZ (K*B*WI*HI)    /* 13,107,200 */

#define NCHUNK 8
#define CHUNK (FEAT_FLAT/NCHUNK)   /* 3136 */
#define CHUNK4 (CHUNK/4)           /* 784 float4 groups */

/* output offsets (floats), in reference return order */
#define O_LOGIT_MU    0
#define O_LOGIT_FEW   8192
#define O_BIG_MASK    8392
#define O_BIG_MASK_NON (O_BIG_MASK + BIG_SZ)
#define O_BIG_IMG     (O_BIG_MASK_NON + BIG_SZ)
#define O_P_MAP       (O_BIG_IMG + BIG_SZ)
#define O_C_FEW       (O_P_MAP + 8192)
#define O_BX          (O_C_FEW + 200)
#define O_BY          (O_BX + 200)
#define O_BW          (O_BY + 200)
#define O_BH          (O_BW + 200)
#define O_Z_SAMPLE    (O_BH + 200)
#define O_KL_LOGIT    (O_Z_SAMPLE + 3200)
#define O_KL_ZWHERE   (O_KL_LOGIT + 8192)
#define O_KL_ZINST    (O_KL_ZWHERE + 800)

__device__ __forceinline__ float sigmoidf_(float x) { return 1.0f / (1.0f + expf(-x)); }
__device__ __forceinline__ float softplusf_(float x) { return fmaxf(x, 0.0f) + log1pf(expf(-fabsf(x))); }

__device__ __forceinline__ float tap256(const float* img, int x, int y) {
    bool in = ((unsigned)x < 256u) && ((unsigned)y < 256u);
    int xc = min(max(x, 0), 255), yc = min(max(y, 0), 255);
    float v = img[xc * 256 + yc];
    return in ? v : 0.0f;
}

__device__ __forceinline__ float tap28(const float* img, int x, int y) {
    bool in = ((unsigned)x < 28u) && ((unsigned)y < 28u);
    int xc = min(max(x, 0), 27), yc = min(max(y, 0), 27);
    float v = img[xc * 28 + yc];
    return in ? v : 0.0f;
}

/* ---------------- kernel M: elementwise logit maps ---------------- */
__global__ void misc_kernel(const float* __restrict__ logit_mu, float* __restrict__ out) {
    int i = blockIdx.x * blockDim.x + threadIdx.x;
    if (i >= B * NBOX) return;
    float x = logit_mu[i];
    out[O_LOGIT_MU + i] = x;
    float p = sigmoidf_(x);
    out[O_P_MAP + i] = p;
    out[O_KL_LOGIT + i] = 0.69314718055994531f + p * logf(p + 1e-8f) + (1.0f - p) * logf(1.0f - p + 1e-8f);
}

/* ---------------- kernel T: per-batch top-k + box params + kl_zwhere ---------------- */
__global__ void topk_kernel(const float* __restrict__ logit_mu,
                            const float* __restrict__ zmu, const float* __restrict__ zstd,
                            const float* __restrict__ w_zw, const float* __restrict__ b_zw,
                            float* __restrict__ out, float* __restrict__ ws_boxes) {
    int b = blockIdx.x;
    int lane = threadIdx.x;          // 64 lanes, one wave
    const float* lg = logit_mu + b * NBOX;
    float vals[16];
    #pragma unroll
    for (int m = 0; m < 16; ++m) vals[m] = lg[m * 64 + lane];
    unsigned taken = 0;
    int sel_idx = 0;

    for (int ks = 0; ks < K; ++ks) {
        float bv = -INFINITY; int bi = 0x7fffffff;
        #pragma unroll
        for (int m = 0; m < 16; ++m) {
            if (!(taken & (1u << m))) {
                float v = vals[m]; int idx = m * 64 + lane;
                if (v > bv || (v == bv && idx < bi)) { bv = v; bi = idx; }
            }
        }
        #pragma unroll
        for (int sh = 32; sh >= 1; sh >>= 1) {
            float ov = __shfl_xor(bv, sh);
            int   oi = __shfl_xor(bi, sh);
            if (ov > bv || (ov == bv && oi < bi)) { bv = ov; bi = oi; }
        }
        if ((bi & 63) == lane) taken |= (1u << (bi >> 6));  // owner marks it used
        if (lane == ks) sel_idx = bi;
        if (lane == 0) {
            out[O_LOGIT_FEW + ks * B + b] = bv;
            out[O_C_FEW + ks * B + b] = sigmoidf_(bv);
        }
    }

    if (lane < K) {
        int idx = sel_idx;
        int w = idx >> 5, h = idx & 31;
        float mu_c[4];
        #pragma unroll
        for (int c = 0; c < 4; ++c) mu_c[c] = zmu[((b * 4 + c) * NW + w) * NH + h];
        float t[4];
        #pragma unroll
        for (int o = 0; o < 4; ++o) {
            float a = b_zw[o];
            #pragma unroll
            for (int c = 0; c < 4; ++c) a = fmaf(mu_c[c], w_zw[o * 4 + c], a);
            t[o] = sigmoidf_(a);
        }
        float bx = (float)WI * ((float)w + t[0]) / (float)NW;
        float by = (float)HI * ((float)h + t[1]) / (float)NH;
        float bw = SMIN + (SMAX - SMIN) * t[2];
        float bh = SMIN + (SMAX - SMIN) * t[3];
        int kb = lane * B + b;
        out[O_BX + kb] = bx;
        out[O_BY + kb] = by;
        out[O_BW + kb] = bw;
        out[O_BH + kb] = bh;
        ((float4*)ws_boxes)[kb] = make_float4(bx, by, bw, bh);
        #pragma unroll
        for (int c = 0; c < 4; ++c) {
            float m = mu_c[c];
            float sd = zstd[((b * 4 + c) * NW + w) * NH + h];
            out[O_KL_ZWHERE + kb * 4 + c] = 0.5f * (sd * sd + m * m - 1.0f) - logf(sd);
        }
    }
}

/* ---------------- kernel C1: fused crop-sample + split-K encoder partials ----------------
   grid = 200 boxes * 8 K-chunks; block 256.
   Each thread handles float4 groups (4 bilinear samples + float4 weight loads). */
__global__ __launch_bounds__(256) void crop_enc_part_kernel(
        const float* __restrict__ features,
        const float* __restrict__ w_mu, const float* __restrict__ w_std,
        const float* __restrict__ ws_boxes, float* __restrict__ ws_part) {
    int blk = blockIdx.x;
    int kb = blk >> 3;
    int chunk = blk & 7;
    int b = kb & 7;
    float4 box = ((const float4*)ws_boxes)[kb];
    float cx = box.x, cy = box.y, cw = box.z, chh = box.w;
    const float* fb = features + (size_t)b * FCH * WI * HI;
    const float4* wm4 = (const float4*)w_mu;
    const float4* ws4 = (const float4*)w_std;
    int base4 = chunk * CHUNK4;

    float accm[DZI], accs[DZI];
    #pragma unroll
    for (int j = 0; j < DZI; ++j) { accm[j] = 0.0f; accs[j] = 0.0f; }

    for (int e = threadIdx.x; e < CHUNK4; e += 256) {
        int i4 = base4 + e;
        int i = i4 * 4;
        float v[4];
        #pragma unroll
        for (int q = 0; q < 4; ++q) {
            unsigned ii = (unsigned)(i + q);
            unsigned c = ii / 784u;
            unsigned s = ii - c * 784u;
            unsigned ix = s / 28u;
            unsigned iy = s - ix * 28u;
            float px = cx - 0.5f * cw + ((float)ix / 27.0f) * cw;
            float py = cy - 0.5f * chh + ((float)iy / 27.0f) * chh;
            const float* img = fb + (size_t)c * (WI * HI);
            float x0f = floorf(px), y0f = floorf(py);
            float fx = px - x0f, fy = py - y0f;
            int x0 = (int)x0f, y0 = (int)y0f;
            float a00 = tap256(img, x0, y0),     a01 = tap256(img, x0, y0 + 1);
            float a10 = tap256(img, x0 + 1, y0), a11 = tap256(img, x0 + 1, y0 + 1);
            v[q] = (1.0f - fx) * ((1.0f - fy) * a00 + fy * a01)
                 +         fx  * ((1.0f - fy) * a10 + fy * a11);
        }
        #pragma unroll
        for (int j = 0; j < DZI; ++j) {
            float4 w4 = wm4[j * (FEAT_FLAT / 4) + i4];
            accm[j] = fmaf(v[0], w4.x, fmaf(v[1], w4.y, fmaf(v[2], w4.z, fmaf(v[3], w4.w, accm[j]))));
            float4 s4 = ws4[j * (FEAT_FLAT / 4) + i4];
            accs[j] = fmaf(v[0], s4.x, fmaf(v[1], s4.y, fmaf(v[2], s4.z, fmaf(v[3], s4.w, accs[j]))));
        }
    }

    #pragma unroll
    for (int j = 0; j < DZI; ++j) {
        #pragma unroll
        for (int sh = 32; sh >= 1; sh >>= 1) {
            accm[j] += __shfl_xor(accm[j], sh);
            accs[j] += __shfl_xor(accs[j], sh);
        }
    }
    __shared__ float red[4][32];
    int wave = threadIdx.x >> 6;
    int lane = threadIdx.x & 63;
    if (lane == 0) {
        #pragma unroll
        for (int j = 0; j < DZI; ++j) { red[wave][j] = accm[j]; red[wave][16 + j] = accs[j]; }
    }
    __syncthreads();
    if (threadIdx.x < 32) {
        int t = threadIdx.x;
        ws_part[blk * 32 + t] = red[0][t] + red[1][t] + red[2][t] + red[3][t];
    }
}

/* ---------------- kernel C2: reduce partials, finish encoder ---------------- */
__global__ void enc_finish_kernel(const float* __restrict__ ws_part,
                                  const float* __restrict__ b_mu, const float* __restrict__ b_std,
                                  float* __restrict__ ws_z, float* __restrict__ out) {
    int kb = blockIdx.x;
    int t = threadIdx.x;   // 64 threads, use 32
    if (t >= 32) return;
    float sum = 0.0f;
    #pragma unroll
    for (int c = 0; c < NCHUNK; ++c) sum += ws_part[(kb * NCHUNK + c) * 32 + t];
    __shared__ float mu[DZI], sp[DZI];
    if (t < DZI) mu[t] = sum + b_mu[t];
    else sp[t - DZI] = sum + b_std[t - DZI];
    __syncthreads();
    if (t < DZI) {
        float m = mu[t];
        float sd = softplusf_(sp[t]);
        out[O_Z_SAMPLE + kb * DZI + t] = m;
        ws_z[kb * DZI + t] = m;
        out[O_KL_ZINST + kb * DZI + t] = 0.5f * (sd * sd + m * m - 1.0f) - logf(sd + 1e-8f);
    }
}

/* ---------------- kernel D: decoder GEMV + activations -> ws_small ---------------- */
__global__ void dec_kernel(const float* __restrict__ ws_z, const float* __restrict__ w_dec,
                           const float* __restrict__ b_dec, float* __restrict__ ws_small) {
    int kb = blockIdx.x;
    __shared__ float z[DZI];
    if (threadIdx.x < DZI) z[threadIdx.x] = ws_z[kb * DZI + threadIdx.x];
    __syncthreads();
    for (int o = threadIdx.x; o < OUT_FLAT; o += 256) {
        float a = b_dec[o];
        #pragma unroll
        for (int j = 0; j < DZI; ++j) a = fmaf(z[j], w_dec[o * DZI + j], a);
        float r = (o < 784) ? softplusf_(a) : sigmoidf_(a);
        ws_small[(size_t)kb * OUT_FLAT + o] = r;
    }
}

/* ---------------- kernel E: uncrop (bilinear) + mask compose ---------------- */
__global__ __launch_bounds__(256) void uncrop_kernel(const float* __restrict__ ws_small,
                                                     const float* __restrict__ ws_boxes,
                                                     float* __restrict__ out) {
    int bu = blockIdx.x;            // b*256 + u
    int b = bu >> 8;
    int u = bu & 255;
    int v = threadIdx.x;

    __shared__ float4 boxes[K];
    if (threadIdx.x < K) boxes[threadIdx.x] = ((const float4*)ws_boxes)[threadIdx.x * B + b];
    __syncthreads();

    float wk[K];
    float sumw = 0.0f;
    #pragma unroll
    for (int k = 0; k < K; ++k) {
        float4 bx = boxes[k];
        float sx = ((float)u - (bx.x - 0.5f * bx.z)) / bx.z * 27.0f;
        float sy = ((float)v - (bx.y - 0.5f * bx.w)) / bx.w * 27.0f;
        float wv = 0.0f, iv = 0.0f;
        if (sx > -1.0f && sx < 28.0f && sy > -1.0f && sy < 28.0f) {
            float x0f = floorf(sx), y0f = floorf(sy);
            float fx = sx - x0f, fy = sy - y0f;
            int x0 = (int)x0f, y0 = (int)y0f;
            const float* p0 = ws_small + (size_t)(k * B + b) * OUT_FLAT;
            const float* p1 = p0 + 784;
            float a00 = tap28(p0, x0, y0),     a01 = tap28(p0, x0, y0 + 1);
            float a10 = tap28(p0, x0 + 1, y0), a11 = tap28(p0, x0 + 1, y0 + 1);
            wv = (1.0f - fx) * ((1.0f - fy) * a00 + fy * a01)
               +         fx  * ((1.0f - fy) * a10 + fy * a11);
            float c00 = tap28(p1, x0, y0),     c01 = tap28(p1, x0, y0 + 1);
            float c10 = tap28(p1, x0 + 1, y0), c11 = tap28(p1, x0 + 1, y0 + 1);
            iv = (1.0f - fx) * ((1.0f - fy) * c00 + fy * c01)
               +         fx  * ((1.0f - fy) * c10 + fy * c11);
        }
        wk[k] = wv;
        sumw += wv;
        size_t base = ((size_t)(k * B + b) * 256 + u) * 256 + v;
        out[O_BIG_IMG + base] = iv;
        out[O_BIG_MASK_NON + base] = tanhf(wv);
    }
    float scale = tanhf(sumw) / fmaxf(sumw, 1e-6f);
    #pragma unroll
    for (int k = 0; k < K; ++k) {
        size_t base = ((size_t)(k * B + b) * 256 + u) * 256 + v;
        out[O_BIG_MASK + base] = wk[k] * scale;
    }
}

extern "C" void kernel_launch(void* const* d_in, const int* in_sizes, int n_in,
                              void* d_out, int out_size, void* d_ws, size_t ws_size,
                              hipStream_t stream) {
    const float* features = (const float*)d_in[1];
    const float* zwhere_mu = (const float*)d_in[2];
    const float* zwhere_std = (const float*)d_in[3];
    const float* logit_mu = (const float*)d_in[4];
    const float* w_zwhere = (const float*)d_in[5];
    const float* b_zwhere = (const float*)d_in[6];
    const float* w_enc_mu = (const float*)d_in[7];
    const float* b_enc_mu = (const float*)d_in[8];
    const float* w_enc_std = (const float*)d_in[9];
    const float* b_enc_std = (const float*)d_in[10];
    const float* w_dec = (const float*)d_in[11];
    const float* b_dec = (const float*)d_in[12];
    float* out = (float*)d_out;

    float* ws_boxes = (float*)d_ws;                   // 800 floats
    float* ws_z     = ws_boxes + 200 * 4;             // 3200 floats
    float* ws_small = ws_z + 200 * DZI;               // 313600 floats
    float* ws_part  = ws_small + 200 * OUT_FLAT;      // 51200 floats

    hipLaunchKernelGGL(misc_kernel, dim3(32), dim3(256), 0, stream, logit_mu, out);
    hipLaunchKernelGGL(topk_kernel, dim3(B), dim3(64), 0, stream,
                       logit_mu, zwhere_mu, zwhere_std, w_zwhere, b_zwhere, out, ws_boxes);
    hipLaunchKernelGGL(crop_enc_part_kernel, dim3(K * B * NCHUNK), dim3(256), 0, stream,
                       features, w_enc_mu, w_enc_std, ws_boxes, ws_part);
    hipLaunchKernelGGL(enc_finish_kernel, dim3(K * B), dim3(64), 0, stream,
                       ws_part, b_enc_mu, b_enc_std, ws_z, out);
    hipLaunchKernelGGL(dec_kernel, dim3(K * B), dim3(256), 0, stream, ws_z, w_dec, b_dec, ws_small);
    hipLaunchKernelGGL(uncrop_kernel, dim3(B * 256), dim3(256), 0, stream, ws_small, ws_boxes, out);
}